// Round 1
// baseline (1068.678 us; speedup 1.0000x reference)
//
#include <hip/hip_runtime.h>

// Problem constants
#define B_SZ 4
#define IN_CH 64
#define OUT_CH 128
#define NHI 163842
#define NLO 40962
#define EPS_GN 1e-5f
#define SLOPE 0.2f

// ---------------------------------------------------------------------------
// 1) Transpose x: (B, 64, NHI) -> xT (B, NHI, 64) via 64x64 LDS tile
// ---------------------------------------------------------------------------
__global__ void k_transpose_x(const float* __restrict__ x, float* __restrict__ xT) {
    __shared__ float t[64][65];
    const int b  = blockIdx.y;
    const int n0 = blockIdx.x * 64;
    const int nn = threadIdx.x & 63;
    const int cq = threadIdx.x >> 6;   // 0..3
#pragma unroll
    for (int r = 0; r < 16; ++r) {
        int c = cq * 16 + r;
        int n = n0 + nn;
        t[c][nn] = (n < NHI) ? x[((long)b * IN_CH + c) * NHI + n] : 0.f;
    }
    __syncthreads();
    const int cc = threadIdx.x & 63;
    const int nq = threadIdx.x >> 6;
#pragma unroll
    for (int r = 0; r < 16; ++r) {
        int nn2 = nq * 16 + r;
        int n = n0 + nn2;
        if (n < NHI) xT[((long)b * NHI + n) * 64 + cc] = t[cc][nn2];
    }
}

// ---------------------------------------------------------------------------
// 2) Transpose W (O, K) -> Wt (K, O=128)
// ---------------------------------------------------------------------------
__global__ void k_transpose_w(const float* __restrict__ W, float* __restrict__ Wt, int K) {
    int i = blockIdx.x * 256 + threadIdx.x;
    if (i >= K * 128) return;
    int o = i & 127;
    int f = i >> 7;
    Wt[i] = W[o * K + f];
}

// ---------------------------------------------------------------------------
// 3) Mean pool: h1[b][n][c] = mean_j xT[b][pool_neigh[n*7+j]][c]
//    one wave per (b,n), lane = c
// ---------------------------------------------------------------------------
__global__ void k_pool(const float* __restrict__ xT, const int* __restrict__ pn,
                       float* __restrict__ h1) {
    int t = blockIdx.x * 256 + threadIdx.x;
    int c = t & 63;
    int n = (t >> 6) % NLO;
    int b = t / (64 * NLO);
    float acc = 0.f;
#pragma unroll
    for (int j = 0; j < 7; ++j) {
        int idx = pn[n * 7 + j];
        acc += xT[((long)b * NHI + idx) * 64 + c];
    }
    h1[((long)b * NLO + n) * 64 + c] = acc * (1.f / 7.f);
}

// ---------------------------------------------------------------------------
// 4) One-ring conv as tiled GEMM.
//    out[b][n][o] = bias[o] + sum_{j,c} feat(b, nbr[n*7+j], c) * Wt[j*CIN+c][o]
//    FUSE: feat = leakyrelu(src*scale[b][c] + shift[b][c])  (gn1 fused into conv2)
//    Tile: 32 nodes x 128 outputs, K-chunks of 32. block=256, micro 4x4.
// ---------------------------------------------------------------------------
template <int CIN, bool FUSE>
__global__ void k_conv(const float* __restrict__ src, const int* __restrict__ nbr,
                       const float* __restrict__ Wt, const float* __restrict__ bias,
                       const float* __restrict__ scale, const float* __restrict__ shift,
                       float* __restrict__ out) {
    const int K = 7 * CIN;
    __shared__ float As[32][36];    // [kk][nn], row stride 36 words (16B-aligned rows)
    __shared__ float Bs[32][128];   // [kk][o]
    const int b   = blockIdx.y;
    const int n0  = blockIdx.x * 32;
    const int tid = threadIdx.x;
    float acc[4][4] = {};

    for (int k0 = 0; k0 < K; k0 += 32) {
        const int j     = k0 / CIN;      // neighbor slot, fixed within chunk
        const int cbase = k0 % CIN;      // channel base, chunk stays inside one j
        // stage A (gathered features): e = tid + i*256 -> kk = e&31, nn = e>>5
#pragma unroll
        for (int i = 0; i < 4; ++i) {
            int e  = tid + i * 256;
            int kk = e & 31;
            int nn = e >> 5;
            int n  = n0 + nn;
            if (n >= NLO) n = NLO - 1;                 // clamp, results masked at store
            int row = nbr[n * 7 + j];
            float v = src[((long)b * NLO + row) * CIN + cbase + kk];
            if (FUSE) {
                int c = cbase + kk;
                v = v * scale[b * OUT_CH + c] + shift[b * OUT_CH + c];
                v = (v >= 0.f) ? v : SLOPE * v;
            }
            As[kk][nn] = v;
        }
        // stage B (weights): e -> o = e&127, kk = e>>7
#pragma unroll
        for (int i = 0; i < 16; ++i) {
            int e  = tid + i * 256;
            int o  = e & 127;
            int kk = e >> 7;
            Bs[kk][o] = Wt[(long)(k0 + kk) * 128 + o];
        }
        __syncthreads();

        const int to = tid & 31;
        const int tn = tid >> 5;
#pragma unroll
        for (int kk = 0; kk < 32; ++kk) {
            float4 a  = *(const float4*)&As[kk][tn * 4];
            float4 b4 = *(const float4*)&Bs[kk][to * 4];
            float av[4] = {a.x, a.y, a.z, a.w};
            float bv[4] = {b4.x, b4.y, b4.z, b4.w};
#pragma unroll
            for (int i = 0; i < 4; ++i)
#pragma unroll
                for (int jj = 0; jj < 4; ++jj) acc[i][jj] += av[i] * bv[jj];
        }
        __syncthreads();
    }

    const int to = tid & 31;
    const int tn = tid >> 5;
    float4 bb = *(const float4*)&bias[to * 4];
    float bv[4] = {bb.x, bb.y, bb.z, bb.w};
#pragma unroll
    for (int i = 0; i < 4; ++i) {
        int n = n0 + tn * 4 + i;
        if (n < NLO) {
            float4 r;
            r.x = acc[i][0] + bv[0];
            r.y = acc[i][1] + bv[1];
            r.z = acc[i][2] + bv[2];
            r.w = acc[i][3] + bv[3];
            *(float4*)&out[((long)b * NLO + n) * 128 + to * 4] = r;
        }
    }
}

// ---------------------------------------------------------------------------
// 5) GroupNorm stats pass 1: per-block partial (sum, sumsq) per (b, g).
//    Deterministic (no atomics): partials -> ws, reduced in finalize.
//    block 256: lane cg = tid&31 owns channels cg*4..cg*4+3 (group g = cg>>3 fixed)
// ---------------------------------------------------------------------------
__global__ void k_stats(const float* __restrict__ y, float* __restrict__ part, int nblk) {
    const int b    = blockIdx.y;
    const int rows = (NLO + nblk - 1) / nblk;
    const int n0   = blockIdx.x * rows;
    const int n1   = min(n0 + rows, NLO);
    const int cg   = threadIdx.x & 31;
    const int rr   = threadIdx.x >> 5;
    float s = 0.f, ss = 0.f;
    for (int n = n0 + rr; n < n1; n += 8) {
        float4 v = *(const float4*)&y[((long)b * NLO + n) * 128 + cg * 4];
        s  += v.x + v.y + v.z + v.w;
        ss += v.x * v.x + v.y * v.y + v.z * v.z + v.w * v.w;
    }
    __shared__ float ls[256], lss[256];
    ls[threadIdx.x]  = s;
    lss[threadIdx.x] = ss;
    __syncthreads();
    if (threadIdx.x < 4) {
        int g = threadIdx.x;
        float as = 0.f, ass = 0.f;
        for (int r = 0; r < 8; ++r)
            for (int c = 0; c < 8; ++c) {
                int t = r * 32 + g * 8 + c;
                as  += ls[t];
                ass += lss[t];
            }
        part[(((long)b * nblk + blockIdx.x) * 4 + g) * 2 + 0] = as;
        part[(((long)b * nblk + blockIdx.x) * 4 + g) * 2 + 1] = ass;
    }
}

// ---------------------------------------------------------------------------
// 6) Finalize stats -> per (b,c) scale/shift.  scale = rstd*w, shift = b - mu*rstd*w
// ---------------------------------------------------------------------------
__global__ void k_finalize(const float* __restrict__ part, int nblk,
                           const float* __restrict__ w, const float* __restrict__ bb,
                           float* __restrict__ scale, float* __restrict__ shift) {
    int i = blockIdx.x * blockDim.x + threadIdx.x;
    if (i >= 512) return;
    int b = i >> 7, c = i & 127, g = c >> 5;
    float s = 0.f, ss = 0.f;
    for (int k = 0; k < nblk; ++k) {
        s  += part[(((long)b * nblk + k) * 4 + g) * 2 + 0];
        ss += part[(((long)b * nblk + k) * 4 + g) * 2 + 1];
    }
    const float cnt = 32.f * NLO;
    float mu  = s / cnt;
    float var = ss / cnt - mu * mu;
    float rs  = rsqrtf(var + EPS_GN);
    float sc  = rs * w[c];
    scale[i] = sc;
    shift[i] = bb[c] - mu * sc;
}

// ---------------------------------------------------------------------------
// 7) Output: gn2 + leakyrelu + transpose (B,N,128) -> (B,128,N) via LDS tile
// ---------------------------------------------------------------------------
__global__ void k_output(const float* __restrict__ y2, const float* __restrict__ scale,
                         const float* __restrict__ shift, float* __restrict__ out) {
    __shared__ float t[32][133];
    const int b   = blockIdx.y;
    const int n0  = blockIdx.x * 32;
    const int tid = threadIdx.x;
    const int c   = tid & 127;
    const int r2  = tid >> 7;
#pragma unroll
    for (int r = 0; r < 32; r += 2) {
        int nn = r + r2;
        int n  = n0 + nn;
        float v = 0.f;
        if (n < NLO) {
            v = y2[((long)b * NLO + n) * 128 + c];
            v = v * scale[b * 128 + c] + shift[b * 128 + c];
            v = (v >= 0.f) ? v : SLOPE * v;
        }
        t[nn][c] = v;
    }
    __syncthreads();
    const int nn = tid & 31;
    const int cq = tid >> 5;
#pragma unroll
    for (int i = 0; i < 16; ++i) {
        int cc = cq * 16 + i;
        int n  = n0 + nn;
        if (n < NLO) out[((long)b * 128 + cc) * NLO + n] = t[nn][cc];
    }
}

// ---------------------------------------------------------------------------
// Launch
// ---------------------------------------------------------------------------
extern "C" void kernel_launch(void* const* d_in, const int* in_sizes, int n_in,
                              void* d_out, int out_size, void* d_ws, size_t ws_size,
                              hipStream_t stream) {
    const float* x   = (const float*)d_in[0];
    const int*   pn  = (const int*)d_in[1];
    const int*   cn  = (const int*)d_in[2];
    const float* W1  = (const float*)d_in[3];
    const float* b1  = (const float*)d_in[4];
    const float* g1w = (const float*)d_in[5];
    const float* g1b = (const float*)d_in[6];
    const float* W2  = (const float*)d_in[7];
    const float* b2  = (const float*)d_in[8];
    const float* g2w = (const float*)d_in[9];
    const float* g2b = (const float*)d_in[10];
    float* out = (float*)d_out;
    float* ws  = (float*)d_ws;

    // Workspace layout (floats). xT region is reused for y1 and y2 after pooling.
    const long SZ_XT = (long)B_SZ * NHI * 64;        // 41,943,552
    const long SZ_H1 = (long)B_SZ * NLO * 64;        // 10,486,272
    const long SZ_Y  = (long)B_SZ * NLO * 128;       // 20,972,544
    const int  NBLK  = 128;                           // stats blocks per b

    const long OFF_XT  = 0;
    const long OFF_H1  = OFF_XT + SZ_XT;
    const long OFF_W1T = OFF_H1 + SZ_H1;             // 448*128 = 57,344
    const long OFF_W2T = OFF_W1T + 57344;            // 896*128 = 114,688
    const long OFF_P1  = OFF_W2T + 114688;           // partials: 4*NBLK*4*2 = 4096
    const long OFF_P2  = OFF_P1 + 4096;
    const long OFF_SC1 = OFF_P2 + 4096;              // 512 scale + 512 shift
    const long OFF_SC2 = OFF_SC1 + 1024;
    const long OFF_Y1  = 0;                           // reuse xT region
    const long OFF_Y2  = OFF_Y1 + SZ_Y;              // spills 1536 floats into dead h1

    float* xT  = ws + OFF_XT;
    float* h1  = ws + OFF_H1;
    float* w1t = ws + OFF_W1T;
    float* w2t = ws + OFF_W2T;
    float* p1  = ws + OFF_P1;
    float* p2  = ws + OFF_P2;
    float* sc1 = ws + OFF_SC1;
    float* sh1 = sc1 + 512;
    float* sc2 = ws + OFF_SC2;
    float* sh2 = sc2 + 512;
    float* y1  = ws + OFF_Y1;
    float* y2  = ws + OFF_Y2;

    // 1. transpose x
    k_transpose_x<<<dim3((NHI + 63) / 64, B_SZ), 256, 0, stream>>>(x, xT);
    // 2. transpose weights
    k_transpose_w<<<(448 * 128 + 255) / 256, 256, 0, stream>>>(W1, w1t, 448);
    k_transpose_w<<<(896 * 128 + 255) / 256, 256, 0, stream>>>(W2, w2t, 896);
    // 3. mean pool -> h1 (node-major)
    k_pool<<<(B_SZ * NLO * 64) / 256, 256, 0, stream>>>(xT, pn, h1);
    // 4. conv1 -> y1 (overwrites dead xT region)
    k_conv<64, false><<<dim3((NLO + 31) / 32, B_SZ), 256, 0, stream>>>(
        h1, cn, w1t, b1, nullptr, nullptr, y1);
    // 5. gn1 stats
    k_stats<<<dim3(NBLK, B_SZ), 256, 0, stream>>>(y1, p1, NBLK);
    k_finalize<<<2, 256, 0, stream>>>(p1, NBLK, g1w, g1b, sc1, sh1);
    // 6. conv2 with fused gn1+leakyrelu on gathered input -> y2
    k_conv<128, true><<<dim3((NLO + 31) / 32, B_SZ), 256, 0, stream>>>(
        y1, cn, w2t, b2, sc1, sh1, y2);
    // 7. gn2 stats
    k_stats<<<dim3(NBLK, B_SZ), 256, 0, stream>>>(y2, p2, NBLK);
    k_finalize<<<2, 256, 0, stream>>>(p2, NBLK, g2w, g2b, sc2, sh2);
    // 8. gn2 + leakyrelu + transpose -> out
    k_output<<<dim3((NLO + 31) / 32, B_SZ), 256, 0, stream>>>(y2, sc2, sh2, out);
}

// Round 2
// 449.270 us; speedup vs baseline: 2.3787x; 2.3787x over previous
//
#include <hip/hip_runtime.h>

#define B_SZ 4
#define IN_CH 64
#define OUT_CH 128
#define NHI 163842
#define NLO 40962
#define EPS_GN 1e-5f
#define SLOPE 0.2f

typedef __attribute__((ext_vector_type(8))) short short8;
typedef __attribute__((ext_vector_type(16))) float f32x16;

__device__ inline ushort f2bf(float f) {
    union { float f; unsigned u; } v; v.f = f;
    unsigned r = v.u + 0x7FFF + ((v.u >> 16) & 1);
    return (ushort)(r >> 16);
}
__device__ inline float bf2f(ushort h) {
    union { unsigned u; float f; } v; v.u = ((unsigned)h) << 16;
    return v.f;
}

// ---------------------------------------------------------------------------
// 1) Transpose x: (B,64,NHI) f32 -> xT (B,NHI,64) bf16
// ---------------------------------------------------------------------------
__global__ void k_transpose_x(const float* __restrict__ x, ushort* __restrict__ xT) {
    __shared__ float t[64][65];
    const int b  = blockIdx.y;
    const int n0 = blockIdx.x * 64;
    const int nn = threadIdx.x & 63;
    const int cq = threadIdx.x >> 6;
#pragma unroll
    for (int r = 0; r < 16; ++r) {
        int c = cq * 16 + r;
        int n = n0 + nn;
        t[c][nn] = (n < NHI) ? x[((long)b * IN_CH + c) * NHI + n] : 0.f;
    }
    __syncthreads();
    const int c2 = (threadIdx.x & 31) * 2;
    const int nq = threadIdx.x >> 5;   // 0..7
#pragma unroll
    for (int r = 0; r < 8; ++r) {
        int nn2 = nq * 8 + r;
        int n = n0 + nn2;
        if (n < NHI) {
            ushort2 o;
            o.x = f2bf(t[c2][nn2]);
            o.y = f2bf(t[c2 + 1][nn2]);
            *(ushort2*)&xT[((long)b * NHI + n) * 64 + c2] = o;
        }
    }
}

// ---------------------------------------------------------------------------
// 2) Pre-tile weights W (O=128, K) f32 -> Wb bf16 in the conv LDS image:
//    Wb[step][kg(8)][o(128)][e(8)]  where k = step*64 + kg*8 + e
// ---------------------------------------------------------------------------
__global__ void k_prep_w(const float* __restrict__ W, ushort* __restrict__ Wb, int K) {
    int i = blockIdx.x * 256 + threadIdx.x;
    if (i >= K * 128) return;
    int k = i / 128, o = i % 128;
    int step = k >> 6, kk = k & 63, kg = kk >> 3, e = kk & 7;
    Wb[(((long)(step * 8 + kg) * 128 + o) * 8) + e] = f2bf(W[(long)o * K + k]);
}

// ---------------------------------------------------------------------------
// 3) Mean pool: gather 7 bf16 rows of xT, mean in f32 -> h1 bf16 (B,NLO,64)
//    8 threads per node, 8 channels (16B) each.
// ---------------------------------------------------------------------------
__global__ void k_pool(const ushort* __restrict__ xT, const int* __restrict__ pn,
                       ushort* __restrict__ h1) {
    long t = (long)blockIdx.x * 256 + threadIdx.x;
    const long total = (long)B_SZ * NLO * 8;
    if (t >= total) return;
    int  cq = (int)(t & 7);
    long bn = t >> 3;                 // b*NLO + n
    int  n  = (int)(bn % NLO);
    int  b  = (int)(bn / NLO);
    float acc[8] = {};
#pragma unroll
    for (int j = 0; j < 7; ++j) {
        int idx = pn[n * 7 + j];
        short8 v = *(const short8*)&xT[((long)b * NHI + idx) * 64 + cq * 8];
#pragma unroll
        for (int e = 0; e < 8; ++e) acc[e] += bf2f((ushort)v[e]);
    }
    short8 o;
#pragma unroll
    for (int e = 0; e < 8; ++e) o[e] = (short)f2bf(acc[e] * (1.f / 7.f));
    *(short8*)&h1[bn * 64 + cq * 8] = o;
}

// ---------------------------------------------------------------------------
// 4) MFMA one-ring conv. src (B,NLO,CIN) bf16 gathered via nbr; Wb pre-tiled.
//    Block: 64 nodes x 128 outs, 4 waves (2x2), wave tile 32x64, BK=64.
//    Epilogue: bias add, bf16 store, per-block GroupNorm partial stats.
// ---------------------------------------------------------------------------
template <int CIN>
__global__ __launch_bounds__(256)
void k_conv_mfma(const ushort* __restrict__ src, const int* __restrict__ nbr,
                 const ushort* __restrict__ Wb, const float* __restrict__ bias,
                 ushort* __restrict__ out, float* __restrict__ part) {
    constexpr int K = 7 * CIN;
    constexpr int NSTEP = K / 64;
    __shared__ ushort Asm[8 * 64 * 8];    // [kg][nn][e]  8KB
    __shared__ ushort Bsm[8 * 128 * 8];   // [kg][o][e]  16KB
    __shared__ float  red[4][4];

    const int b    = blockIdx.y;
    const int n0   = blockIdx.x * 64;
    const int tid  = threadIdx.x;
    const int lane = tid & 63;
    const int wave = tid >> 6;       // 0..3
    const int wr   = wave >> 1, wc = wave & 1;

    // staging roles: thread quad covers one node's 2x16B chunks
    const int s_nn = tid >> 2;       // 0..63
    const int s_kq = tid & 3;        // kg in {s_kq, s_kq+4}
    int nrow = n0 + s_nn; if (nrow >= NLO) nrow = NLO - 1;
    const int* nbr_row = &nbr[nrow * 7];

    f32x16 acc0 = {}; f32x16 acc1 = {};
    const long srcb = (long)b * NLO * CIN;

    const int arow  = wr * 32 + (lane & 31);
    const int bcol0 = wc * 64 + (lane & 31);
    const int khalf = lane >> 5;

    for (int step = 0; step < NSTEP; ++step) {
        int j, cbase;
        if (CIN == 64) { j = step; cbase = 0; }
        else           { j = step >> 1; cbase = (step & 1) * 64; }
        int row = nbr_row[j];
        const ushort* sp = &src[srcb + (long)row * CIN + cbase + s_kq * 8];
        short8 a0 = *(const short8*)sp;
        short8 a1 = *(const short8*)(sp + 32);
        const ushort* wp = &Wb[(long)step * 8192 + tid * 32];
        short8 w0 = *(const short8*)(wp);
        short8 w1 = *(const short8*)(wp + 8);
        short8 w2 = *(const short8*)(wp + 16);
        short8 w3 = *(const short8*)(wp + 24);
        __syncthreads();   // previous iteration's LDS reads done
        *(short8*)&Asm[(s_kq * 64 + s_nn) * 8]       = a0;
        *(short8*)&Asm[((s_kq + 4) * 64 + s_nn) * 8] = a1;
        *(short8*)&Bsm[tid * 32]      = w0;
        *(short8*)&Bsm[tid * 32 + 8]  = w1;
        *(short8*)&Bsm[tid * 32 + 16] = w2;
        *(short8*)&Bsm[tid * 32 + 24] = w3;
        __syncthreads();
#pragma unroll
        for (int kh = 0; kh < 4; ++kh) {
            int kg = 2 * kh + khalf;
            short8 af  = *(const short8*)&Asm[(kg * 64 + arow) * 8];
            short8 bf0 = *(const short8*)&Bsm[(kg * 128 + bcol0) * 8];
            short8 bf1 = *(const short8*)&Bsm[(kg * 128 + bcol0 + 32) * 8];
            acc0 = __builtin_amdgcn_mfma_f32_32x32x16_bf16(af, bf0, acc0, 0, 0, 0);
            acc1 = __builtin_amdgcn_mfma_f32_32x32x16_bf16(af, bf1, acc1, 0, 0, 0);
        }
    }

    // epilogue: bias, store bf16, partial stats per group
    const float bias0 = bias[wc * 64 + (lane & 31)];
    const float bias1 = bias[wc * 64 + 32 + (lane & 31)];
    float s0 = 0.f, q0 = 0.f, s1 = 0.f, q1 = 0.f;
#pragma unroll
    for (int r = 0; r < 16; ++r) {
        int rrow = (r & 3) + 8 * (r >> 2) + 4 * khalf + wr * 32;
        int n = n0 + rrow;
        float v0 = acc0[r] + bias0;
        float v1 = acc1[r] + bias1;
        if (n < NLO) {
            long o = ((long)b * NLO + n) * 128 + wc * 64 + (lane & 31);
            out[o]      = f2bf(v0);
            out[o + 32] = f2bf(v1);
            s0 += v0; q0 += v0 * v0;
            s1 += v1; q1 += v1 * v1;
        }
    }
#pragma unroll
    for (int off = 32; off > 0; off >>= 1) {
        s0 += __shfl_down(s0, off); q0 += __shfl_down(q0, off);
        s1 += __shfl_down(s1, off); q1 += __shfl_down(q1, off);
    }
    if (lane == 0) { red[wave][0] = s0; red[wave][1] = q0; red[wave][2] = s1; red[wave][3] = q1; }
    __syncthreads();
    if (tid < 8) {
        int g = tid >> 1, isq = tid & 1;
        int wcg = g >> 1, ct = g & 1;
        float v = red[0 * 2 + wcg][ct * 2 + isq] + red[1 * 2 + wcg][ct * 2 + isq];
        part[(((long)b * gridDim.x + blockIdx.x) * 4 + g) * 2 + isq] = v;
    }
}

// ---------------------------------------------------------------------------
// 5) Finalize stats -> per (b,c) scale/shift
// ---------------------------------------------------------------------------
__global__ void k_finalize(const float* __restrict__ part, int nblk,
                           const float* __restrict__ w, const float* __restrict__ bb,
                           float* __restrict__ scale, float* __restrict__ shift) {
    int i = blockIdx.x * 256 + threadIdx.x;
    if (i >= 512) return;
    int b = i >> 7, c = i & 127, g = c >> 5;
    float s = 0.f, ss = 0.f;
    for (int k = 0; k < nblk; ++k) {
        s  += part[(((long)b * nblk + k) * 4 + g) * 2 + 0];
        ss += part[(((long)b * nblk + k) * 4 + g) * 2 + 1];
    }
    const float cnt = 32.f * NLO;
    float mu  = s / cnt;
    float var = ss / cnt - mu * mu;
    float rs  = rsqrtf(var + EPS_GN);
    float sc  = rs * w[c];
    scale[i] = sc;
    shift[i] = bb[c] - mu * sc;
}

// ---------------------------------------------------------------------------
// 6) Elementwise gn+leakyrelu: y (B,NLO,128) bf16 -> yp bf16
// ---------------------------------------------------------------------------
__global__ void k_gnapply(const ushort* __restrict__ y, const float* __restrict__ sc,
                          const float* __restrict__ sh, ushort* __restrict__ yp) {
    long t = (long)blockIdx.x * 256 + threadIdx.x;
    const long total = (long)B_SZ * NLO * 16;
    if (t >= total) return;
    int  c8 = (int)(t & 15);
    long bn = t >> 4;
    int  b  = (int)(bn / NLO);
    short8 v = *(const short8*)&y[bn * 128 + c8 * 8];
    short8 o;
#pragma unroll
    for (int e = 0; e < 8; ++e) {
        int c = c8 * 8 + e;
        float f = bf2f((ushort)v[e]) * sc[b * 128 + c] + sh[b * 128 + c];
        f = (f >= 0.f) ? f : SLOPE * f;
        o[e] = (short)f2bf(f);
    }
    *(short8*)&yp[bn * 128 + c8 * 8] = o;
}

// ---------------------------------------------------------------------------
// 7) Output: gn2 + leakyrelu + transpose (B,N,128) bf16 -> (B,128,N) f32
// ---------------------------------------------------------------------------
__global__ void k_output(const ushort* __restrict__ y2, const float* __restrict__ scale,
                         const float* __restrict__ shift, float* __restrict__ out) {
    __shared__ float t[32][129];
    const int b   = blockIdx.y;
    const int n0  = blockIdx.x * 32;
    const int tid = threadIdx.x;
    const int c   = tid & 127;
    const int r2  = tid >> 7;
    const float sc = scale[b * 128 + c], sh = shift[b * 128 + c];
#pragma unroll
    for (int r = 0; r < 32; r += 2) {
        int nn = r + r2;
        int n  = n0 + nn;
        float v = 0.f;
        if (n < NLO) {
            v = bf2f(y2[((long)b * NLO + n) * 128 + c]);
            v = v * sc + sh;
            v = (v >= 0.f) ? v : SLOPE * v;
        }
        t[nn][c] = v;
    }
    __syncthreads();
    const int nn = tid & 31;
    const int cq = tid >> 5;
#pragma unroll
    for (int i = 0; i < 16; ++i) {
        int cc = cq * 16 + i;
        int n  = n0 + nn;
        if (n < NLO) out[((long)b * 128 + cc) * NLO + n] = t[nn][cc];
    }
}

// ---------------------------------------------------------------------------
// Launch
// ---------------------------------------------------------------------------
extern "C" void kernel_launch(void* const* d_in, const int* in_sizes, int n_in,
                              void* d_out, int out_size, void* d_ws, size_t ws_size,
                              hipStream_t stream) {
    const float* x   = (const float*)d_in[0];
    const int*   pn  = (const int*)d_in[1];
    const int*   cn  = (const int*)d_in[2];
    const float* W1  = (const float*)d_in[3];
    const float* b1  = (const float*)d_in[4];
    const float* g1w = (const float*)d_in[5];
    const float* g1b = (const float*)d_in[6];
    const float* W2  = (const float*)d_in[7];
    const float* b2  = (const float*)d_in[8];
    const float* g2w = (const float*)d_in[9];
    const float* g2b = (const float*)d_in[10];
    float* out = (float*)d_out;
    char*  base = (char*)d_ws;

    // Byte layout (region A reused: xT dead after pool -> y1, y1p)
    ushort* xT  = (ushort*)(base + 0);           // 83,887,104 B
    ushort* y1  = (ushort*)(base + 0);           // 41,945,088 B
    ushort* y1p = (ushort*)(base + 44000000);    // 41,945,088 B
    ushort* h1  = (ushort*)(base + 88000000);    // 20,972,544 B
    ushort* y2  = (ushort*)(base + 110000000);   // 41,945,088 B
    ushort* wb1 = (ushort*)(base + 152000000);   // 114,688 B
    ushort* wb2 = (ushort*)(base + 152200000);   // 229,376 B
    float*  p1  = (float*)(base + 152500000);    // 82,048 B
    float*  p2  = (float*)(base + 152600000);    // 82,048 B
    float*  sc1 = (float*)(base + 152700000);
    float*  sh1 = sc1 + 512;
    float*  sc2 = (float*)(base + 152710000);
    float*  sh2 = sc2 + 512;

    const int NBLK = (NLO + 63) / 64;  // 641 conv blocks per batch

    k_transpose_x<<<dim3((NHI + 63) / 64, B_SZ), 256, 0, stream>>>(x, xT);
    k_prep_w<<<(448 * 128 + 255) / 256, 256, 0, stream>>>(W1, wb1, 448);
    k_prep_w<<<(896 * 128 + 255) / 256, 256, 0, stream>>>(W2, wb2, 896);
    k_pool<<<(int)(((long)B_SZ * NLO * 8 + 255) / 256), 256, 0, stream>>>(xT, pn, h1);
    k_conv_mfma<64><<<dim3(NBLK, B_SZ), 256, 0, stream>>>(h1, cn, wb1, b1, y1, p1);
    k_finalize<<<2, 256, 0, stream>>>(p1, NBLK, g1w, g1b, sc1, sh1);
    k_gnapply<<<(int)(((long)B_SZ * NLO * 16 + 255) / 256), 256, 0, stream>>>(y1, sc1, sh1, y1p);
    k_conv_mfma<128><<<dim3(NBLK, B_SZ), 256, 0, stream>>>(y1p, cn, wb2, b2, y2, p2);
    k_finalize<<<2, 256, 0, stream>>>(p2, NBLK, g2w, g2b, sc2, sh2);
    k_output<<<dim3((NLO + 31) / 32, B_SZ), 256, 0, stream>>>(y2, sc2, sh2, out);
}

// Round 3
// 267.548 us; speedup vs baseline: 3.9943x; 1.6792x over previous
//
#include <hip/hip_runtime.h>

#define B_SZ 4
#define IN_CH 64
#define OUT_CH 128
#define NHI 163842
#define NLO 40962
#define EPS_GN 1e-5f
#define SLOPE 0.2f

typedef __attribute__((ext_vector_type(8))) short short8;
typedef __attribute__((ext_vector_type(16))) float f32x16;

__device__ inline ushort f2bf(float f) {
    union { float f; unsigned u; } v; v.f = f;
    unsigned r = v.u + 0x7FFF + ((v.u >> 16) & 1);
    return (ushort)(r >> 16);
}
__device__ inline float bf2f(ushort h) {
    union { unsigned u; float f; } v; v.u = ((unsigned)h) << 16;
    return v.f;
}

// ---------------------------------------------------------------------------
// 1) Transpose x: (B,64,NHI) f32 -> xT (B,NHI,64) bf16. float4 loads,
//    short8 stores (16B/lane both directions).
// ---------------------------------------------------------------------------
__global__ void k_transpose_x(const float* __restrict__ x, ushort* __restrict__ xT) {
    __shared__ float t[64][65];
    const int b   = blockIdx.y;
    const int n0  = blockIdx.x * 64;
    const int tid = threadIdx.x;
    const int nq  = tid & 15;        // float4 chunk along n
    const int c0  = tid >> 4;        // 0..15
    const bool full = (n0 + 64) <= NHI;
    if (full) {
#pragma unroll
        for (int r = 0; r < 4; ++r) {
            int c = c0 + r * 16;
            float4 v = *(const float4*)&x[((long)b * IN_CH + c) * NHI + n0 + nq * 4];
            t[c][nq * 4 + 0] = v.x; t[c][nq * 4 + 1] = v.y;
            t[c][nq * 4 + 2] = v.z; t[c][nq * 4 + 3] = v.w;
        }
    } else {
        for (int r = 0; r < 4; ++r) {
            int c = c0 + r * 16;
            for (int e = 0; e < 4; ++e) {
                int n = n0 + nq * 4 + e;
                t[c][nq * 4 + e] = (n < NHI) ? x[((long)b * IN_CH + c) * NHI + n] : 0.f;
            }
        }
    }
    __syncthreads();
    const int n  = tid >> 2;          // 0..63
    const int cc = (tid & 3) * 16;    // 16-channel chunk
    if (n0 + n < NHI) {
        short8 o0, o1;
#pragma unroll
        for (int e = 0; e < 8; ++e) {
            o0[e] = (short)f2bf(t[cc + e][n]);
            o1[e] = (short)f2bf(t[cc + 8 + e][n]);
        }
        ushort* p = &xT[((long)b * NHI + n0 + n) * 64 + cc];
        *(short8*)p = o0;
        *(short8*)(p + 8) = o1;
    }
}

// ---------------------------------------------------------------------------
// 2) Pre-tile weights W (O=128, K) f32 -> Wb bf16 in the conv LDS image:
//    Wb[step][kg(8)][o(128)][e(8)]  where k = step*64 + kg*8 + e
// ---------------------------------------------------------------------------
__global__ void k_prep_w(const float* __restrict__ W, ushort* __restrict__ Wb, int K) {
    int i = blockIdx.x * 256 + threadIdx.x;
    if (i >= K * 128) return;
    int k = i / 128, o = i % 128;
    int step = k >> 6, kk = k & 63, kg = kk >> 3, e = kk & 7;
    Wb[(((long)(step * 8 + kg) * 128 + o) * 8) + e] = f2bf(W[(long)o * K + k]);
}

// ---------------------------------------------------------------------------
// 3) Mean pool: gather 7 bf16 rows of xT, mean in f32 -> h1 bf16 (B,NLO,64)
// ---------------------------------------------------------------------------
__global__ void k_pool(const ushort* __restrict__ xT, const int* __restrict__ pn,
                       ushort* __restrict__ h1) {
    long t = (long)blockIdx.x * 256 + threadIdx.x;
    const long total = (long)B_SZ * NLO * 8;
    if (t >= total) return;
    int  cq = (int)(t & 7);
    long bn = t >> 3;
    int  n  = (int)(bn % NLO);
    int  b  = (int)(bn / NLO);
    float acc[8] = {};
#pragma unroll
    for (int j = 0; j < 7; ++j) {
        int idx = pn[n * 7 + j];
        short8 v = *(const short8*)&xT[((long)b * NHI + idx) * 64 + cq * 8];
#pragma unroll
        for (int e = 0; e < 8; ++e) acc[e] += bf2f((ushort)v[e]);
    }
    short8 o;
#pragma unroll
    for (int e = 0; e < 8; ++e) o[e] = (short)f2bf(acc[e] * (1.f / 7.f));
    *(short8*)&h1[bn * 64 + cq * 8] = o;
}

// ---------------------------------------------------------------------------
// 4) MFMA one-ring conv (unchanged from R2).
// ---------------------------------------------------------------------------
template <int CIN>
__global__ __launch_bounds__(256)
void k_conv_mfma(const ushort* __restrict__ src, const int* __restrict__ nbr,
                 const ushort* __restrict__ Wb, const float* __restrict__ bias,
                 ushort* __restrict__ out, float* __restrict__ part) {
    constexpr int K = 7 * CIN;
    constexpr int NSTEP = K / 64;
    __shared__ ushort Asm[8 * 64 * 8];    // [kg][nn][e]  8KB
    __shared__ ushort Bsm[8 * 128 * 8];   // [kg][o][e]  16KB
    __shared__ float  red[4][4];

    const int b    = blockIdx.y;
    const int n0   = blockIdx.x * 64;
    const int tid  = threadIdx.x;
    const int lane = tid & 63;
    const int wave = tid >> 6;
    const int wr   = wave >> 1, wc = wave & 1;

    const int s_nn = tid >> 2;
    const int s_kq = tid & 3;
    int nrow = n0 + s_nn; if (nrow >= NLO) nrow = NLO - 1;
    const int* nbr_row = &nbr[nrow * 7];

    f32x16 acc0 = {}; f32x16 acc1 = {};
    const long srcb = (long)b * NLO * CIN;

    const int arow  = wr * 32 + (lane & 31);
    const int bcol0 = wc * 64 + (lane & 31);
    const int khalf = lane >> 5;

    for (int step = 0; step < NSTEP; ++step) {
        int j, cbase;
        if (CIN == 64) { j = step; cbase = 0; }
        else           { j = step >> 1; cbase = (step & 1) * 64; }
        int row = nbr_row[j];
        const ushort* sp = &src[srcb + (long)row * CIN + cbase + s_kq * 8];
        short8 a0 = *(const short8*)sp;
        short8 a1 = *(const short8*)(sp + 32);
        const ushort* wp = &Wb[(long)step * 8192 + tid * 32];
        short8 w0 = *(const short8*)(wp);
        short8 w1 = *(const short8*)(wp + 8);
        short8 w2 = *(const short8*)(wp + 16);
        short8 w3 = *(const short8*)(wp + 24);
        __syncthreads();
        *(short8*)&Asm[(s_kq * 64 + s_nn) * 8]       = a0;
        *(short8*)&Asm[((s_kq + 4) * 64 + s_nn) * 8] = a1;
        *(short8*)&Bsm[tid * 32]      = w0;
        *(short8*)&Bsm[tid * 32 + 8]  = w1;
        *(short8*)&Bsm[tid * 32 + 16] = w2;
        *(short8*)&Bsm[tid * 32 + 24] = w3;
        __syncthreads();
#pragma unroll
        for (int kh = 0; kh < 4; ++kh) {
            int kg = 2 * kh + khalf;
            short8 af  = *(const short8*)&Asm[(kg * 64 + arow) * 8];
            short8 bf0 = *(const short8*)&Bsm[(kg * 128 + bcol0) * 8];
            short8 bf1 = *(const short8*)&Bsm[(kg * 128 + bcol0 + 32) * 8];
            acc0 = __builtin_amdgcn_mfma_f32_32x32x16_bf16(af, bf0, acc0, 0, 0, 0);
            acc1 = __builtin_amdgcn_mfma_f32_32x32x16_bf16(af, bf1, acc1, 0, 0, 0);
        }
    }

    const float bias0 = bias[wc * 64 + (lane & 31)];
    const float bias1 = bias[wc * 64 + 32 + (lane & 31)];
    float s0 = 0.f, q0 = 0.f, s1 = 0.f, q1 = 0.f;
#pragma unroll
    for (int r = 0; r < 16; ++r) {
        int rrow = (r & 3) + 8 * (r >> 2) + 4 * khalf + wr * 32;
        int n = n0 + rrow;
        float v0 = acc0[r] + bias0;
        float v1 = acc1[r] + bias1;
        if (n < NLO) {
            long o = ((long)b * NLO + n) * 128 + wc * 64 + (lane & 31);
            out[o]      = f2bf(v0);
            out[o + 32] = f2bf(v1);
            s0 += v0; q0 += v0 * v0;
            s1 += v1; q1 += v1 * v1;
        }
    }
#pragma unroll
    for (int off = 32; off > 0; off >>= 1) {
        s0 += __shfl_down(s0, off); q0 += __shfl_down(q0, off);
        s1 += __shfl_down(s1, off); q1 += __shfl_down(q1, off);
    }
    if (lane == 0) { red[wave][0] = s0; red[wave][1] = q0; red[wave][2] = s1; red[wave][3] = q1; }
    __syncthreads();
    if (tid < 8) {
        int g = tid >> 1, isq = tid & 1;
        int wcg = g >> 1, ct = g & 1;
        float v = red[0 * 2 + wcg][ct * 2 + isq] + red[1 * 2 + wcg][ct * 2 + isq];
        part[(((long)b * gridDim.x + blockIdx.x) * 4 + g) * 2 + isq] = v;
    }
}

// ---------------------------------------------------------------------------
// 5) Finalize stats -> per (b,c) scale/shift. One block per (b,g); 256
//    threads stride the partials; tree reduce. (Was 2 blocks total, 95us!)
// ---------------------------------------------------------------------------
__global__ void k_finalize(const float* __restrict__ part, int nblk,
                           const float* __restrict__ w, const float* __restrict__ bb,
                           float* __restrict__ scale, float* __restrict__ shift) {
    const int b = blockIdx.x >> 2, g = blockIdx.x & 3;
    const int tid = threadIdx.x;
    float s = 0.f, ss = 0.f;
    for (int k = tid; k < nblk; k += 256) {
        s  += part[(((long)b * nblk + k) * 4 + g) * 2 + 0];
        ss += part[(((long)b * nblk + k) * 4 + g) * 2 + 1];
    }
#pragma unroll
    for (int off = 32; off > 0; off >>= 1) {
        s += __shfl_down(s, off); ss += __shfl_down(ss, off);
    }
    __shared__ float red[8];
    __shared__ float fin[2];
    const int wave = tid >> 6, lane = tid & 63;
    if (lane == 0) { red[wave * 2] = s; red[wave * 2 + 1] = ss; }
    __syncthreads();
    if (tid == 0) {
        float as = red[0] + red[2] + red[4] + red[6];
        float aq = red[1] + red[3] + red[5] + red[7];
        const float cnt = 32.f * NLO;
        float mu  = as / cnt;
        float var = aq / cnt - mu * mu;
        fin[0] = mu; fin[1] = rsqrtf(var + EPS_GN);
    }
    __syncthreads();
    if (tid < 32) {
        int c = g * 32 + tid;
        float sc = fin[1] * w[c];
        scale[b * 128 + c] = sc;
        shift[b * 128 + c] = bb[c] - fin[0] * sc;
    }
}

// ---------------------------------------------------------------------------
// 6) Elementwise gn+leakyrelu: y (B,NLO,128) bf16 -> yp bf16
// ---------------------------------------------------------------------------
__global__ void k_gnapply(const ushort* __restrict__ y, const float* __restrict__ sc,
                          const float* __restrict__ sh, ushort* __restrict__ yp) {
    long t = (long)blockIdx.x * 256 + threadIdx.x;
    const long total = (long)B_SZ * NLO * 16;
    if (t >= total) return;
    int  c8 = (int)(t & 15);
    long bn = t >> 4;
    int  b  = (int)(bn / NLO);
    short8 v = *(const short8*)&y[bn * 128 + c8 * 8];
    short8 o;
#pragma unroll
    for (int e = 0; e < 8; ++e) {
        int c = c8 * 8 + e;
        float f = bf2f((ushort)v[e]) * sc[b * 128 + c] + sh[b * 128 + c];
        f = (f >= 0.f) ? f : SLOPE * f;
        o[e] = (short)f2bf(f);
    }
    *(short8*)&yp[bn * 128 + c8 * 8] = o;
}

// ---------------------------------------------------------------------------
// 7) Output: gn2 + leakyrelu + transpose (B,N,128) bf16 -> (B,128,N) f32.
//    short8 loads; float2 stores (rows only 8B-aligned: NLO%4==2).
// ---------------------------------------------------------------------------
__global__ void k_output(const ushort* __restrict__ y2, const float* __restrict__ scale,
                         const float* __restrict__ shift, float* __restrict__ out) {
    __shared__ float t[32][129];
    const int b   = blockIdx.y;
    const int n0  = blockIdx.x * 32;
    const int tid = threadIdx.x;
    const float* scb = &scale[b * 128];
    const float* shb = &shift[b * 128];
    const int c8 = (tid & 15) * 8;
#pragma unroll
    for (int r = 0; r < 2; ++r) {
        int nn = (tid >> 4) + r * 16;
        int n  = n0 + nn;
        if (n < NLO) {
            short8 v = *(const short8*)&y2[((long)b * NLO + n) * 128 + c8];
#pragma unroll
            for (int e = 0; e < 8; ++e) {
                int c = c8 + e;
                float f = bf2f((ushort)v[e]) * scb[c] + shb[c];
                t[nn][c] = (f >= 0.f) ? f : SLOPE * f;
            }
        } else {
#pragma unroll
            for (int e = 0; e < 8; ++e) t[nn][c8 + e] = 0.f;
        }
    }
    __syncthreads();
    const int n4 = (tid & 7) * 4;
    const bool full = (n0 + 32) <= NLO;
#pragma unroll
    for (int r = 0; r < 4; ++r) {
        int c = (tid >> 3) + r * 32;
        long o = ((long)b * 128 + c) * NLO + n0 + n4;
        if (full) {
            float2 v0 = make_float2(t[n4][c], t[n4 + 1][c]);
            float2 v1 = make_float2(t[n4 + 2][c], t[n4 + 3][c]);
            *(float2*)&out[o]     = v0;
            *(float2*)&out[o + 2] = v1;
        } else {
            for (int e = 0; e < 4; ++e)
                if (n0 + n4 + e < NLO) out[o + e] = t[n4 + e][c];
        }
    }
}

// ---------------------------------------------------------------------------
// Launch
// ---------------------------------------------------------------------------
extern "C" void kernel_launch(void* const* d_in, const int* in_sizes, int n_in,
                              void* d_out, int out_size, void* d_ws, size_t ws_size,
                              hipStream_t stream) {
    const float* x   = (const float*)d_in[0];
    const int*   pn  = (const int*)d_in[1];
    const int*   cn  = (const int*)d_in[2];
    const float* W1  = (const float*)d_in[3];
    const float* b1  = (const float*)d_in[4];
    const float* g1w = (const float*)d_in[5];
    const float* g1b = (const float*)d_in[6];
    const float* W2  = (const float*)d_in[7];
    const float* b2  = (const float*)d_in[8];
    const float* g2w = (const float*)d_in[9];
    const float* g2b = (const float*)d_in[10];
    float* out = (float*)d_out;
    char*  base = (char*)d_ws;

    ushort* xT  = (ushort*)(base + 0);           // 83,887,104 B
    ushort* y1  = (ushort*)(base + 0);           // reuse (xT dead after pool)
    ushort* y1p = (ushort*)(base + 44000000);
    ushort* h1  = (ushort*)(base + 88000000);
    ushort* y2  = (ushort*)(base + 110000000);
    ushort* wb1 = (ushort*)(base + 152000000);
    ushort* wb2 = (ushort*)(base + 152200000);
    float*  p1  = (float*)(base + 152500000);
    float*  p2  = (float*)(base + 152600000);
    float*  sc1 = (float*)(base + 152700000);
    float*  sh1 = sc1 + 512;
    float*  sc2 = (float*)(base + 152710000);
    float*  sh2 = sc2 + 512;

    const int NBLK = (NLO + 63) / 64;  // 641 conv blocks per batch

    k_transpose_x<<<dim3((NHI + 63) / 64, B_SZ), 256, 0, stream>>>(x, xT);
    k_prep_w<<<(448 * 128 + 255) / 256, 256, 0, stream>>>(W1, wb1, 448);
    k_prep_w<<<(896 * 128 + 255) / 256, 256, 0, stream>>>(W2, wb2, 896);
    k_pool<<<(int)(((long)B_SZ * NLO * 8 + 255) / 256), 256, 0, stream>>>(xT, pn, h1);
    k_conv_mfma<64><<<dim3(NBLK, B_SZ), 256, 0, stream>>>(h1, cn, wb1, b1, y1, p1);
    k_finalize<<<16, 256, 0, stream>>>(p1, NBLK, g1w, g1b, sc1, sh1);
    k_gnapply<<<(int)(((long)B_SZ * NLO * 16 + 255) / 256), 256, 0, stream>>>(y1, sc1, sh1, y1p);
    k_conv_mfma<128><<<dim3(NBLK, B_SZ), 256, 0, stream>>>(y1p, cn, wb2, b2, y2, p2);
    k_finalize<<<16, 256, 0, stream>>>(p2, NBLK, g2w, g2b, sc2, sh2);
    k_output<<<dim3((NLO + 31) / 32, B_SZ), 256, 0, stream>>>(y2, sc2, sh2, out);
}

// Round 4
// 248.022 us; speedup vs baseline: 4.3088x; 1.0787x over previous
//
#include <hip/hip_runtime.h>

#define B_SZ 4
#define IN_CH 64
#define OUT_CH 128
#define NHI 163842
#define NLO 40962
#define EPS_GN 1e-5f
#define SLOPE 0.2f

typedef __attribute__((ext_vector_type(8))) short short8;
typedef __attribute__((ext_vector_type(16))) float f32x16;

__device__ inline ushort f2bf(float f) {
    union { float f; unsigned u; } v; v.f = f;
    unsigned r = v.u + 0x7FFF + ((v.u >> 16) & 1);
    return (ushort)(r >> 16);
}
__device__ inline float bf2f(ushort h) {
    union { unsigned u; float f; } v; v.u = ((unsigned)h) << 16;
    return v.f;
}

// ---------------------------------------------------------------------------
// 1) Transpose x: (B,64,NHI) f32 -> xT (B,NHI,64) bf16. float4 loads,
//    short8 stores.
// ---------------------------------------------------------------------------
__global__ void k_transpose_x(const float* __restrict__ x, ushort* __restrict__ xT) {
    __shared__ float t[64][65];
    const int b   = blockIdx.y;
    const int n0  = blockIdx.x * 64;
    const int tid = threadIdx.x;
    const int nq  = tid & 15;
    const int c0  = tid >> 4;
    const bool full = (n0 + 64) <= NHI;
    if (full) {
#pragma unroll
        for (int r = 0; r < 4; ++r) {
            int c = c0 + r * 16;
            float4 v = *(const float4*)&x[((long)b * IN_CH + c) * NHI + n0 + nq * 4];
            t[c][nq * 4 + 0] = v.x; t[c][nq * 4 + 1] = v.y;
            t[c][nq * 4 + 2] = v.z; t[c][nq * 4 + 3] = v.w;
        }
    } else {
        for (int r = 0; r < 4; ++r) {
            int c = c0 + r * 16;
            for (int e = 0; e < 4; ++e) {
                int n = n0 + nq * 4 + e;
                t[c][nq * 4 + e] = (n < NHI) ? x[((long)b * IN_CH + c) * NHI + n] : 0.f;
            }
        }
    }
    __syncthreads();
    const int n  = tid >> 2;
    const int cc = (tid & 3) * 16;
    if (n0 + n < NHI) {
        short8 o0, o1;
#pragma unroll
        for (int e = 0; e < 8; ++e) {
            o0[e] = (short)f2bf(t[cc + e][n]);
            o1[e] = (short)f2bf(t[cc + 8 + e][n]);
        }
        ushort* p = &xT[((long)b * NHI + n0 + n) * 64 + cc];
        *(short8*)p = o0;
        *(short8*)(p + 8) = o1;
    }
}

// ---------------------------------------------------------------------------
// 2) Pre-tile weights W (O=128, K) f32 -> Wb bf16 in the conv LDS image:
//    Wb[step][kg(8)][o(128)][e(8)]  where k = step*64 + kg*8 + e
// ---------------------------------------------------------------------------
__global__ void k_prep_w(const float* __restrict__ W, ushort* __restrict__ Wb, int K) {
    int i = blockIdx.x * 256 + threadIdx.x;
    if (i >= K * 128) return;
    int k = i / 128, o = i % 128;
    int step = k >> 6, kk = k & 63, kg = kk >> 3, e = kk & 7;
    Wb[(((long)(step * 8 + kg) * 128 + o) * 8) + e] = f2bf(W[(long)o * K + k]);
}

// ---------------------------------------------------------------------------
// 3) Mean pool: gather 7 bf16 rows of xT, mean in f32 -> h1 bf16 (B,NLO,64)
// ---------------------------------------------------------------------------
__global__ void k_pool(const ushort* __restrict__ xT, const int* __restrict__ pn,
                       ushort* __restrict__ h1) {
    long t = (long)blockIdx.x * 256 + threadIdx.x;
    const long total = (long)B_SZ * NLO * 8;
    if (t >= total) return;
    int  cq = (int)(t & 7);
    long bn = t >> 3;
    int  n  = (int)(bn % NLO);
    int  b  = (int)(bn / NLO);
    float acc[8] = {};
#pragma unroll
    for (int j = 0; j < 7; ++j) {
        int idx = pn[n * 7 + j];
        short8 v = *(const short8*)&xT[((long)b * NHI + idx) * 64 + cq * 8];
#pragma unroll
        for (int e = 0; e < 8; ++e) acc[e] += bf2f((ushort)v[e]);
    }
    short8 o;
#pragma unroll
    for (int e = 0; e < 8; ++e) o[e] = (short)f2bf(acc[e] * (1.f / 7.f));
    *(short8*)&h1[bn * 64 + cq * 8] = o;
}

// ---------------------------------------------------------------------------
// 4) MFMA one-ring conv, 128 nodes x 128 outs, 512 threads (8 waves, 4x2),
//    double-buffered LDS, ONE barrier per K-step, prefetch issued after the
//    barrier (so the barrier's vmcnt drain doesn't eat it) and before MFMA.
// ---------------------------------------------------------------------------
template <int CIN>
__global__ __launch_bounds__(512, 4)
void k_conv_mfma(const ushort* __restrict__ src, const int* __restrict__ nbr,
                 const ushort* __restrict__ Wb, const float* __restrict__ bias,
                 ushort* __restrict__ out, float* __restrict__ part) {
    constexpr int K = 7 * CIN;
    constexpr int NSTEP = K / 64;
    __shared__ ushort Asm[2][8 * 128 * 8];   // 32KB  [kg][nn][e]
    __shared__ ushort Bsm[2][8 * 128 * 8];   // 32KB  [kg][o][e]
    __shared__ float  red[8][4];

    const int b    = blockIdx.y;
    const int n0   = blockIdx.x * 128;
    const int tid  = threadIdx.x;
    const int lane = tid & 63;
    const int wave = tid >> 6;               // 0..7
    const int wr   = wave >> 1, wc = wave & 1;

    // A staging: 4 threads per node, 2 chunks of 8 channels (kg s_kq, s_kq+4)
    const int s_nn = tid >> 2;               // 0..127
    const int s_kq = tid & 3;
    int nrow = n0 + s_nn; if (nrow >= NLO) nrow = NLO - 1;
    const int* nbr_row = &nbr[nrow * 7];

    f32x16 acc0 = {}, acc1 = {};
    const long srcb = (long)b * NLO * CIN;

    const int arow  = wr * 32 + (lane & 31);
    const int bcol0 = wc * 64 + (lane & 31);
    const int khalf = lane >> 5;

    short8 a0, a1, w0, w1;
    // prologue load, step 0
    {
        int j = 0, cbase = 0;
        const ushort* sp = &src[srcb + (long)nbr_row[j] * CIN + cbase + s_kq * 8];
        a0 = *(const short8*)sp;
        a1 = *(const short8*)(sp + 32);
        const ushort* wp = &Wb[tid * 16];
        w0 = *(const short8*)wp;
        w1 = *(const short8*)(wp + 8);
    }

    for (int step = 0; step < NSTEP; ++step) {
        const int cur = step & 1;
        *(short8*)&Asm[cur][(s_kq * 128 + s_nn) * 8]       = a0;
        *(short8*)&Asm[cur][((s_kq + 4) * 128 + s_nn) * 8] = a1;
        *(short8*)&Bsm[cur][tid * 16]     = w0;
        *(short8*)&Bsm[cur][tid * 16 + 8] = w1;
        __syncthreads();
        if (step + 1 < NSTEP) {
            int s = step + 1, j, cbase;
            if (CIN == 64) { j = s; cbase = 0; }
            else           { j = s >> 1; cbase = (s & 1) * 64; }
            const ushort* sp = &src[srcb + (long)nbr_row[j] * CIN + cbase + s_kq * 8];
            a0 = *(const short8*)sp;
            a1 = *(const short8*)(sp + 32);
            const ushort* wp = &Wb[(long)s * 8192 + tid * 16];
            w0 = *(const short8*)wp;
            w1 = *(const short8*)(wp + 8);
        }
#pragma unroll
        for (int kh = 0; kh < 4; ++kh) {
            int kg = 2 * kh + khalf;
            short8 af  = *(const short8*)&Asm[cur][(kg * 128 + arow) * 8];
            short8 bf0 = *(const short8*)&Bsm[cur][(kg * 128 + bcol0) * 8];
            short8 bf1 = *(const short8*)&Bsm[cur][(kg * 128 + bcol0 + 32) * 8];
            acc0 = __builtin_amdgcn_mfma_f32_32x32x16_bf16(af, bf0, acc0, 0, 0, 0);
            acc1 = __builtin_amdgcn_mfma_f32_32x32x16_bf16(af, bf1, acc1, 0, 0, 0);
        }
        // no second barrier: next step writes the other buffer; the next
        // barrier orders those writes after this step's (drained) reads.
    }

    // epilogue: bias, bf16 store, per-block GroupNorm partials
    const float bias0 = bias[wc * 64 + (lane & 31)];
    const float bias1 = bias[wc * 64 + 32 + (lane & 31)];
    float s0 = 0.f, q0 = 0.f, s1 = 0.f, q1 = 0.f;
#pragma unroll
    for (int r = 0; r < 16; ++r) {
        int rrow = (r & 3) + 8 * (r >> 2) + 4 * khalf + wr * 32;
        int n = n0 + rrow;
        float v0 = acc0[r] + bias0;
        float v1 = acc1[r] + bias1;
        if (n < NLO) {
            long o = ((long)b * NLO + n) * 128 + wc * 64 + (lane & 31);
            out[o]      = f2bf(v0);
            out[o + 32] = f2bf(v1);
            s0 += v0; q0 += v0 * v0;
            s1 += v1; q1 += v1 * v1;
        }
    }
#pragma unroll
    for (int off = 32; off > 0; off >>= 1) {
        s0 += __shfl_down(s0, off); q0 += __shfl_down(q0, off);
        s1 += __shfl_down(s1, off); q1 += __shfl_down(q1, off);
    }
    if (lane == 0) { red[wave][0] = s0; red[wave][1] = q0; red[wave][2] = s1; red[wave][3] = q1; }
    __syncthreads();
    if (tid < 8) {
        int g = tid >> 1, isq = tid & 1;
        int wcg = g >> 1, ct = g & 1;
        float v = 0.f;
#pragma unroll
        for (int w = 0; w < 4; ++w) v += red[w * 2 + wcg][ct * 2 + isq];
        part[(((long)b * gridDim.x + blockIdx.x) * 4 + g) * 2 + isq] = v;
    }
}

// ---------------------------------------------------------------------------
// 5) Finalize stats -> per (b,c) scale/shift. One block per (b,g).
// ---------------------------------------------------------------------------
__global__ void k_finalize(const float* __restrict__ part, int nblk,
                           const float* __restrict__ w, const float* __restrict__ bb,
                           float* __restrict__ scale, float* __restrict__ shift) {
    const int b = blockIdx.x >> 2, g = blockIdx.x & 3;
    const int tid = threadIdx.x;
    float s = 0.f, ss = 0.f;
    for (int k = tid; k < nblk; k += 256) {
        s  += part[(((long)b * nblk + k) * 4 + g) * 2 + 0];
        ss += part[(((long)b * nblk + k) * 4 + g) * 2 + 1];
    }
#pragma unroll
    for (int off = 32; off > 0; off >>= 1) {
        s += __shfl_down(s, off); ss += __shfl_down(ss, off);
    }
    __shared__ float red[8];
    __shared__ float fin[2];
    const int wave = tid >> 6, lane = tid & 63;
    if (lane == 0) { red[wave * 2] = s; red[wave * 2 + 1] = ss; }
    __syncthreads();
    if (tid == 0) {
        float as = red[0] + red[2] + red[4] + red[6];
        float aq = red[1] + red[3] + red[5] + red[7];
        const float cnt = 32.f * NLO;
        float mu  = as / cnt;
        float var = aq / cnt - mu * mu;
        fin[0] = mu; fin[1] = rsqrtf(var + EPS_GN);
    }
    __syncthreads();
    if (tid < 32) {
        int c = g * 32 + tid;
        float sc = fin[1] * w[c];
        scale[b * 128 + c] = sc;
        shift[b * 128 + c] = bb[c] - fin[0] * sc;
    }
}

// ---------------------------------------------------------------------------
// 6) Elementwise gn+leakyrelu: y (B,NLO,128) bf16 -> yp bf16
// ---------------------------------------------------------------------------
__global__ void k_gnapply(const ushort* __restrict__ y, const float* __restrict__ sc,
                          const float* __restrict__ sh, ushort* __restrict__ yp) {
    long t = (long)blockIdx.x * 256 + threadIdx.x;
    const long total = (long)B_SZ * NLO * 16;
    if (t >= total) return;
    int  c8 = (int)(t & 15);
    long bn = t >> 4;
    int  b  = (int)(bn / NLO);
    short8 v = *(const short8*)&y[bn * 128 + c8 * 8];
    short8 o;
#pragma unroll
    for (int e = 0; e < 8; ++e) {
        int c = c8 * 8 + e;
        float f = bf2f((ushort)v[e]) * sc[b * 128 + c] + sh[b * 128 + c];
        f = fmaxf(f, SLOPE * f);
        o[e] = (short)f2bf(f);
    }
    *(short8*)&yp[bn * 128 + c8 * 8] = o;
}

// ---------------------------------------------------------------------------
// 7) Output: gn2 + leakyrelu + transpose (B,N,128) bf16 -> (B,128,N) f32.
// ---------------------------------------------------------------------------
__global__ void k_output(const ushort* __restrict__ y2, const float* __restrict__ scale,
                         const float* __restrict__ shift, float* __restrict__ out) {
    __shared__ float t[32][129];
    const int b   = blockIdx.y;
    const int n0  = blockIdx.x * 32;
    const int tid = threadIdx.x;
    const float* scb = &scale[b * 128];
    const float* shb = &shift[b * 128];
    const int c8 = (tid & 15) * 8;
#pragma unroll
    for (int r = 0; r < 2; ++r) {
        int nn = (tid >> 4) + r * 16;
        int n  = n0 + nn;
        if (n < NLO) {
            short8 v = *(const short8*)&y2[((long)b * NLO + n) * 128 + c8];
#pragma unroll
            for (int e = 0; e < 8; ++e) {
                int c = c8 + e;
                float f = bf2f((ushort)v[e]) * scb[c] + shb[c];
                t[nn][c] = fmaxf(f, SLOPE * f);
            }
        } else {
#pragma unroll
            for (int e = 0; e < 8; ++e) t[nn][c8 + e] = 0.f;
        }
    }
    __syncthreads();
    const int n4 = (tid & 7) * 4;
    const bool full = (n0 + 32) <= NLO;
#pragma unroll
    for (int r = 0; r < 4; ++r) {
        int c = (tid >> 3) + r * 32;
        long o = ((long)b * 128 + c) * NLO + n0 + n4;
        if (full) {
            float2 v0 = make_float2(t[n4][c], t[n4 + 1][c]);
            float2 v1 = make_float2(t[n4 + 2][c], t[n4 + 3][c]);
            *(float2*)&out[o]     = v0;
            *(float2*)&out[o + 2] = v1;
        } else {
            for (int e = 0; e < 4; ++e)
                if (n0 + n4 + e < NLO) out[o + e] = t[n4 + e][c];
        }
    }
}

// ---------------------------------------------------------------------------
// Launch
// ---------------------------------------------------------------------------
extern "C" void kernel_launch(void* const* d_in, const int* in_sizes, int n_in,
                              void* d_out, int out_size, void* d_ws, size_t ws_size,
                              hipStream_t stream) {
    const float* x   = (const float*)d_in[0];
    const int*   pn  = (const int*)d_in[1];
    const int*   cn  = (const int*)d_in[2];
    const float* W1  = (const float*)d_in[3];
    const float* b1  = (const float*)d_in[4];
    const float* g1w = (const float*)d_in[5];
    const float* g1b = (const float*)d_in[6];
    const float* W2  = (const float*)d_in[7];
    const float* b2  = (const float*)d_in[8];
    const float* g2w = (const float*)d_in[9];
    const float* g2b = (const float*)d_in[10];
    float* out = (float*)d_out;
    char*  base = (char*)d_ws;

    ushort* xT  = (ushort*)(base + 0);           // 83,887,104 B
    ushort* y1  = (ushort*)(base + 0);           // reuse (xT dead after pool)
    ushort* y1p = (ushort*)(base + 44000000);
    ushort* h1  = (ushort*)(base + 88000000);
    ushort* y2  = (ushort*)(base + 110000000);
    ushort* wb1 = (ushort*)(base + 152000000);
    ushort* wb2 = (ushort*)(base + 152200000);
    float*  p1  = (float*)(base + 152500000);
    float*  p2  = (float*)(base + 152600000);
    float*  sc1 = (float*)(base + 152700000);
    float*  sh1 = sc1 + 512;
    float*  sc2 = (float*)(base + 152710000);
    float*  sh2 = sc2 + 512;

    const int NBLK = (NLO + 127) / 128;  // 321 conv blocks per batch

    k_transpose_x<<<dim3((NHI + 63) / 64, B_SZ), 256, 0, stream>>>(x, xT);
    k_prep_w<<<(448 * 128 + 255) / 256, 256, 0, stream>>>(W1, wb1, 448);
    k_prep_w<<<(896 * 128 + 255) / 256, 256, 0, stream>>>(W2, wb2, 896);
    k_pool<<<(int)(((long)B_SZ * NLO * 8 + 255) / 256), 256, 0, stream>>>(xT, pn, h1);
    k_conv_mfma<64><<<dim3(NBLK, B_SZ), 512, 0, stream>>>(h1, cn, wb1, b1, y1, p1);
    k_finalize<<<16, 256, 0, stream>>>(p1, NBLK, g1w, g1b, sc1, sh1);
    k_gnapply<<<(int)(((long)B_SZ * NLO * 16 + 255) / 256), 256, 0, stream>>>(y1, sc1, sh1, y1p);
    k_conv_mfma<128><<<dim3(NBLK, B_SZ), 512, 0, stream>>>(y1p, cn, wb2, b2, y2, p2);
    k_finalize<<<16, 256, 0, stream>>>(p2, NBLK, g2w, g2b, sc2, sh2);
    k_output<<<dim3((NLO + 31) / 32, B_SZ), 256, 0, stream>>>(y2, sc2, sh2, out);
}